// Round 1
// baseline (10905.947 us; speedup 1.0000x reference)
//
#include <hip/hip_runtime.h>
#include <hip/hip_bf16.h>
#include <stdint.h>
#include <math.h>

// ElmoLstm on MI355X.
// L=2 layers x 2 dirs, B=64, T=128, D=H=512, C=4096.
// Per step/dir: gates = [h|x] @ [Wh|Wi]^T + b  (bf16 MFMA, fp32 acc),
// elementwise LSTM cell w/ clip, then h = clip(act @ Wp^T).
// Weights converted fp32->bf16 once per call into d_ws.

#define BB 64
#define TT 128
#define DD 512
#define HH 512
#define CC 4096

typedef __bf16 v8bf __attribute__((ext_vector_type(8)));
typedef float  v4f  __attribute__((ext_vector_type(4)));
typedef short  v8s  __attribute__((ext_vector_type(8)));

__device__ __forceinline__ uint16_t f2bf(float f) {
    unsigned int x = __float_as_uint(f);
    unsigned int r = (x + 0x7fffu + ((x >> 16) & 1u)) >> 16;
    return (uint16_t)r;
}
__device__ __forceinline__ float sigm(float x) { return 1.0f / (1.0f + __expf(-x)); }

// ---------------- weight conversion ----------------
// Wf[(l,dir,j)][k] : k<512 -> Wh[(l,dir,j)][k], k>=512 -> Wi[(l,dir,j)][k-512]
__global__ __launch_bounds__(256) void k_conv_wfull(
        const float* __restrict__ Wi, const float* __restrict__ Wh,
        uint16_t* __restrict__ Wf) {
    size_t i   = (size_t)blockIdx.x * blockDim.x + threadIdx.x; // 8,388,608 threads
    size_t idx = i * 8;
    size_t row = idx >> 10;
    int    k   = (int)(idx & 1023);
    const float* s = (k < 512) ? (Wh + row * 512 + k) : (Wi + row * 512 + (k - 512));
    float4 f0 = ((const float4*)s)[0];
    float4 f1 = ((const float4*)s)[1];
    v8s v;
    v[0]=f2bf(f0.x); v[1]=f2bf(f0.y); v[2]=f2bf(f0.z); v[3]=f2bf(f0.w);
    v[4]=f2bf(f1.x); v[5]=f2bf(f1.y); v[6]=f2bf(f1.z); v[7]=f2bf(f1.w);
    ((v8s*)Wf)[i] = v;
}

__global__ __launch_bounds__(256) void k_conv_plain(
        const float* __restrict__ src, uint16_t* __restrict__ dst, int n8) {
    int i = blockIdx.x * blockDim.x + threadIdx.x;
    if (i >= n8) return;
    const float4* s = (const float4*)(src + (size_t)i * 8);
    float4 f0 = s[0];
    float4 f1 = s[1];
    v8s v;
    v[0]=f2bf(f0.x); v[1]=f2bf(f0.y); v[2]=f2bf(f0.z); v[3]=f2bf(f0.w);
    v[4]=f2bf(f1.x); v[5]=f2bf(f1.y); v[6]=f2bf(f1.z); v[7]=f2bf(f1.w);
    ((v8s*)dst)[i] = v;
}

// ---------------- gates + elementwise ----------------
// grid (128 cell-tiles, 2 dirs), 256 thr. Block computes gates for 32 cells
// x 4 gate groups x 64 batch. Wave w == gate group w (rows j = w*4096+cell).
// A[64][1024] = [h_prev bf16 | x_t bf16]; B rows from Wl. Epilogue via LDS.
__global__ __launch_bounds__(256) void k_gates(
        const uint16_t* __restrict__ Wl,    // [2][16384][1024] this layer
        const float*    __restrict__ bl,    // [2][16384]
        const uint16_t* __restrict__ hprev, // [2][64][512]
        const uint16_t* __restrict__ xs0,   // dir0 x source [64][128][512]
        const uint16_t* __restrict__ xs1,   // dir1 x source
        float*    __restrict__ c_state,     // [2][64][4096]
        uint16_t* __restrict__ act,         // [2][64][4096]
        float*    __restrict__ cs_out,      // [64][8192] this layer
        int t_step, int flags) {            // bit0 first, bit1 last
    const int dir  = blockIdx.y;
    const int bx   = blockIdx.x;
    const int tid  = threadIdx.x;
    const int w    = tid >> 6;      // wave == gate group
    const int lane = tid & 63;
    const int col  = lane & 15;
    const int quad = lane >> 4;
    const int tt   = dir ? (127 - t_step) : t_step;
    const bool first = (flags & 1), last = (flags & 2);

    const uint16_t* xsrc = dir ? xs1 : xs0;
    const uint16_t* hp   = hprev + (size_t)dir * BB * HH;
    const uint16_t* Wd   = Wl + (size_t)dir * 16384 * 1024;

    v4f acc[4][2] = {};
    const uint16_t* brow[2];
#pragma unroll
    for (int nt = 0; nt < 2; ++nt) {
        int j = w * 4096 + bx * 32 + nt * 16 + col;
        brow[nt] = Wd + (size_t)j * 1024;
    }

    int ks0 = first ? 16 : 0; // h0 == 0: skip h half of K
    for (int ks = ks0; ks < 32; ++ks) {
        int k = ks * 32 + quad * 8;
        v8bf a[4], bf[2];
        if (k < 512) {
#pragma unroll
            for (int mt = 0; mt < 4; ++mt) {
                int m = mt * 16 + col;
                a[mt] = *(const v8bf*)(hp + (size_t)m * HH + k);
            }
        } else {
#pragma unroll
            for (int mt = 0; mt < 4; ++mt) {
                int m = mt * 16 + col;
                a[mt] = *(const v8bf*)(xsrc + ((size_t)m * TT + tt) * DD + (k - 512));
            }
        }
#pragma unroll
        for (int nt = 0; nt < 2; ++nt) bf[nt] = *(const v8bf*)(brow[nt] + k);
#pragma unroll
        for (int mt = 0; mt < 4; ++mt)
#pragma unroll
            for (int nt = 0; nt < 2; ++nt)
                acc[mt][nt] = __builtin_amdgcn_mfma_f32_16x16x32_bf16(
                        a[mt], bf[nt], acc[mt][nt], 0, 0, 0);
    }

    __shared__ float gt[4][64][33]; // [gate][m][cell_local], +1 pad
#pragma unroll
    for (int mt = 0; mt < 4; ++mt)
#pragma unroll
        for (int nt = 0; nt < 2; ++nt)
#pragma unroll
            for (int r = 0; r < 4; ++r)
                gt[w][mt * 16 + quad * 4 + r][nt * 16 + col] = acc[mt][nt][r];
    __syncthreads();

    const float* bd = bl + (size_t)dir * 16384;
#pragma unroll
    for (int i = 0; i < 8; ++i) {
        int idx  = i * 256 + tid;       // 2048 (m,cell) pairs
        int m    = idx >> 5;
        int cl   = idx & 31;
        int cell = bx * 32 + cl;
        float xi = gt[0][m][cl] + bd[cell];
        float xf = gt[1][m][cl] + bd[4096 + cell];
        float xg = gt[2][m][cl] + bd[8192 + cell];
        float xo = gt[3][m][cl] + bd[12288 + cell];
        float iv = sigm(xi), fv = sigm(xf), ov = sigm(xo);
        float gv = tanhf(xg);
        size_t cidx = ((size_t)dir * BB + m) * CC + cell;
        float cold = first ? 0.0f : c_state[cidx];
        float cn = fminf(fmaxf(iv * gv + fv * cold, -3.0f), 3.0f);
        c_state[cidx] = cn;
        act[cidx] = f2bf(ov * tanhf(cn));
        if (last) cs_out[(size_t)m * 8192 + dir * 4096 + cell] = cn;
    }
}

// ---------------- projection ----------------
// grid (32 n-tiles, 4 m-tiles, 2 dirs), 256 thr. One 16x16 tile per block,
// K=4096 split over 4 waves, LDS reduce, clip, write outputs.
__global__ __launch_bounds__(256) void k_proj(
        const uint16_t* __restrict__ Wpl,  // [2][512][4096] this layer
        const uint16_t* __restrict__ act,  // [2][64][4096]
        uint16_t* __restrict__ hout,       // [2][64][512]
        uint16_t* __restrict__ hseq,       // [2][64][128][512] or null (layer0 only)
        float* __restrict__ seq_out,       // this layer's [64][128][1024]
        const float* __restrict__ resid,   // layer0 seq base or null
        float* __restrict__ hs_out,        // [64][1024] this layer
        int t_step, int last) {
    const int bn   = blockIdx.x;
    const int bm   = blockIdx.y;
    const int dir  = blockIdx.z;
    const int tid  = threadIdx.x;
    const int w    = tid >> 6;
    const int lane = tid & 63;
    const int col  = lane & 15;
    const int quad = lane >> 4;
    const int tt   = dir ? (127 - t_step) : t_step;

    const uint16_t* A  = act + ((size_t)dir * BB + bm * 16 + col) * CC;
    const uint16_t* Br = Wpl + ((size_t)dir * HH + bn * 16 + col) * CC;

    v4f acc = {};
#pragma unroll 8
    for (int ks = w * 32; ks < w * 32 + 32; ++ks) {
        int k = ks * 32 + quad * 8;
        v8bf a  = *(const v8bf*)(A + k);
        v8bf bb = *(const v8bf*)(Br + k);
        acc = __builtin_amdgcn_mfma_f32_16x16x32_bf16(a, bb, acc, 0, 0, 0);
    }
    __shared__ float red[4][256];
#pragma unroll
    for (int r = 0; r < 4; ++r)
        red[w][(quad * 4 + r) * 16 + col] = acc[r];
    __syncthreads();

    int e = tid; // 256 outputs per block
    float s = red[0][e] + red[1][e] + red[2][e] + red[3][e];
    float h = fminf(fmaxf(s, -3.0f), 3.0f);
    int ml = e >> 4, nl = e & 15;
    int m = bm * 16 + ml, n = bn * 16 + nl;
    uint16_t hb = f2bf(h);
    hout[((size_t)dir * BB + m) * HH + n] = hb;
    if (hseq) hseq[(((size_t)dir * BB + m) * TT + tt) * HH + n] = hb;
    size_t so = ((size_t)m * TT + tt) * 1024 + (size_t)dir * 512 + n;
    float outv = h;
    if (resid) outv += resid[so];
    seq_out[so] = outv;
    if (last) hs_out[(size_t)m * 1024 + dir * 512 + n] = h;
}

// ---------------- launch ----------------
extern "C" void kernel_launch(void* const* d_in, const int* in_sizes, int n_in,
                              void* d_out, int out_size, void* d_ws, size_t ws_size,
                              hipStream_t stream) {
    const float* x  = (const float*)d_in[0];
    const float* Wi = (const float*)d_in[1];
    const float* Wh = (const float*)d_in[2];
    const float* bb = (const float*)d_in[3];
    const float* Wp = (const float*)d_in[4];
    float* out = (float*)d_out;

    char* ws = (char*)d_ws;
    size_t off = 0;
    auto take = [&](size_t bytes) -> char* {
        char* p = ws + off;
        off = (off + bytes + 255) & ~(size_t)255;
        return p;
    };
    uint16_t* Wf   = (uint16_t*)take(2ull * 2 * 16384 * 1024 * 2); // 134 MB
    uint16_t* Wpb  = (uint16_t*)take(2ull * 2 * 512 * 4096 * 2);   // 16.8 MB
    uint16_t* xb   = (uint16_t*)take((size_t)BB * TT * DD * 2);    // 8.4 MB
    uint16_t* hseq = (uint16_t*)take(2ull * BB * TT * HH * 2);     // 16.8 MB
    uint16_t* hb   = (uint16_t*)take(2ull * BB * HH * 2);
    uint16_t* actb = (uint16_t*)take(2ull * BB * CC * 2);
    float*    cst  = (float*)take(2ull * BB * CC * 4);

    hipLaunchKernelGGL(k_conv_wfull, dim3(32768), dim3(256), 0, stream, Wi, Wh, Wf);
    hipLaunchKernelGGL(k_conv_plain, dim3(4096), dim3(256), 0, stream, Wp, Wpb,
                       2 * 2 * 512 * 4096 / 8);
    hipLaunchKernelGGL(k_conv_plain, dim3(2048), dim3(256), 0, stream, x, xb,
                       BB * TT * DD / 8);

    const size_t SEQ = (size_t)BB * TT * 1024; // 8,388,608 per layer
    float* hs_base = out + 2 * SEQ;            // +16,777,216
    float* cs_base = hs_base + 2ull * BB * 1024;

    for (int l = 0; l < 2; ++l) {
        const uint16_t* Wl  = Wf + (size_t)l * 2 * 16384 * 1024;
        const float*    blp = bb + (size_t)l * 2 * 16384;
        const uint16_t* Wpl = Wpb + (size_t)l * 2 * 512 * 4096;
        const uint16_t* xs0 = l ? hseq : xb;
        const uint16_t* xs1 = l ? hseq + (size_t)BB * TT * HH : xb;
        float* seq_l = out + (size_t)l * SEQ;
        float* cs_l  = cs_base + (size_t)l * BB * 8192;
        float* hs_l  = hs_base + (size_t)l * BB * 1024;
        for (int t = 0; t < TT; ++t) {
            int flags = (t == 0 ? 1 : 0) | (t == TT - 1 ? 2 : 0);
            hipLaunchKernelGGL(k_gates, dim3(128, 2), dim3(256), 0, stream,
                               Wl, blp, hb, xs0, xs1, cst, actb, cs_l, t, flags);
            hipLaunchKernelGGL(k_proj, dim3(32, 4, 2), dim3(256), 0, stream,
                               Wpl, actb, hb,
                               (l == 0) ? hseq : (uint16_t*)nullptr,
                               seq_l,
                               (l == 1) ? (const float*)out : (const float*)nullptr,
                               hs_l, t, (t == TT - 1) ? 1 : 0);
        }
    }
}